// Round 3
// baseline (938.984 us; speedup 1.0000x reference)
//
#include <hip/hip_runtime.h>
#include <hip/hip_bf16.h>

typedef __bf16 bf16_t;
typedef __bf16 bf16x4 __attribute__((ext_vector_type(4)));
typedef __bf16 bf16x8 __attribute__((ext_vector_type(8)));
typedef float f32x4 __attribute__((ext_vector_type(4)));

#define NTOK 4096   // B*T
#define TT   512
#define HH   1024
#define VV   32000

#define BM 256
#define BN 256
#define BK 64       // two K-slices of 32
#define NKT 16      // K-tiles = HH/BK

#define GLOBAL_AS(p) ((const __attribute__((address_space(1))) void*)(const void*)(p))
#define LDS_AS(p)    ((__attribute__((address_space(3))) void*)(void*)(p))

// ---------------------------------------------------------------------------
// f32 -> bf16 bulk convert (memory-bound pre-pass).
// ---------------------------------------------------------------------------
__global__ __launch_bounds__(256)
void grpo_cvt_bf16(const float* __restrict__ src, bf16_t* __restrict__ dst, int n4)
{
    int i = blockIdx.x * 256 + threadIdx.x;
    const int stride = gridDim.x * 256;
    for (; i < n4; i += stride) {
        f32x4 v = *(const f32x4*)(src + (size_t)i * 4);
        bf16x4 b;
#pragma unroll
        for (int e = 0; e < 4; ++e) b[e] = (bf16_t)v[e];
        *(bf16x4*)(dst + (size_t)i * 4) = b;
    }
}

// ---------------------------------------------------------------------------
// 8-phase 256x256 GEMM + logsumexp partial + selected-logit gather.
// LDS ring: lds[buf][mat][kh] = 8 regions of [256 rows][32 K-cols] bf16 (16KB).
// Swizzle (T2): physical 16B slot = logical_slot ^ (row & 3)  (involution).
// gload_lds writes linearly; source address pre-swizzled; reads swizzled.
// ---------------------------------------------------------------------------
__device__ __forceinline__ bf16_t* region_ptr(bf16_t* lds0, int b, int mat, int kh)
{
    return lds0 + ((b * 2 + mat) * 2 + kh) * 8192;   // 256*32 bf16 per region
}

template<int SBUF, int SMAT, int SKH>
__device__ __forceinline__ void stage_region(bf16_t* lds0, const bf16_t* __restrict__ src,
                                             int row0, int kc, int tid, int wid)
{
    bf16_t* reg = region_ptr(lds0, SBUF, SMAT, SKH);
#pragma unroll
    for (int i = 0; i < 2; ++i) {
        const int f     = i * 512 + tid;            // physical 16B chunk 0..1023
        const int row   = f >> 2;                   // 0..255
        const int lslot = (f & 3) ^ (row & 3);      // inverse-swizzled source slot
        const bf16_t* g = src + (size_t)(row0 + row) * HH + kc + lslot * 8;
        bf16_t* l = reg + (i * 512 + wid * 64) * 8; // wave-uniform; HW adds lane*16B
        __builtin_amdgcn_global_load_lds(GLOBAL_AS(g), LDS_AS(l), 16, 0, 0);
    }
}

template<int RBUF, int RKH, int MG, int SBUF, int SMAT, int SKH, int SOFF, bool VMW>
__device__ __forceinline__ void phase(bf16_t* lds0, f32x4 (&acc)[8][4],
                                      const bf16_t* __restrict__ Xb,
                                      const bf16_t* __restrict__ Wb,
                                      int m0, int n0, int te,
                                      int arow, int brow, int ps, int tid, int wid)
{
    const bf16_t* Ar = region_ptr(lds0, RBUF, 0, RKH);
    const bf16_t* Br = region_ptr(lds0, RBUF, 1, RKH);

    bf16x8 af[4], bfr[4];
#pragma unroll
    for (int m = 0; m < 4; ++m)
        af[m] = *(const bf16x8*)(Ar + (arow + MG * 64 + m * 16) * 32 + ps * 8);
#pragma unroll
    for (int n = 0; n < 4; ++n)
        bfr[n] = *(const bf16x8*)(Br + (brow + n * 16) * 32 + ps * 8);

    // prefetch one region for a future K-tile (lands >=5 phases later)
    stage_region<SBUF, SMAT, SKH>(lds0, SMAT ? Wb : Xb, SMAT ? n0 : m0,
                                  ((te + SOFF) & (NKT - 1)) * BK + SKH * 32, tid, wid);

    asm volatile("s_barrier" ::: "memory");
    asm volatile("s_waitcnt lgkmcnt(0)" ::: "memory");
    __builtin_amdgcn_sched_barrier(0);

    __builtin_amdgcn_s_setprio(1);
#pragma unroll
    for (int m = 0; m < 4; ++m)
#pragma unroll
        for (int n = 0; n < 4; ++n)
            acc[MG * 4 + m][n] = __builtin_amdgcn_mfma_f32_16x16x32_bf16(
                af[m], bfr[n], acc[MG * 4 + m][n], 0, 0, 0);
    __builtin_amdgcn_s_setprio(0);

    if (VMW) asm volatile("s_waitcnt vmcnt(8)" ::: "memory");  // counted, never 0
    asm volatile("s_barrier" ::: "memory");
}

__global__ __launch_bounds__(512)
void grpo_gemm8(const bf16_t* __restrict__ Xb, const bf16_t* __restrict__ Wb,
                const int* __restrict__ ids,
                float* __restrict__ S, float* __restrict__ SEL)
{
    __shared__ bf16_t lds[2][2][2][256][32];   // 128 KiB
    bf16_t* lds0 = &lds[0][0][0][0][0];

    const int tid  = threadIdx.x;
    const int lane = tid & 63;
    const int wid  = tid >> 6;
    const int wr   = wid >> 2;        // 0..1  (M split)
    const int wc   = wid & 3;         // 0..3  (N split)
    const int l16  = lane & 15;
    const int g    = lane >> 4;       // logical K-slot
    const int ps   = g ^ (l16 & 3);   // physical (swizzled) K-slot
    const int arow = wr * 128 + l16;
    const int brow = wc * 64 + l16;

    const int m0 = blockIdx.x * BM;
    const int n0 = blockIdx.y * BN;

    f32x4 acc[8][4];
#pragma unroll
    for (int m = 0; m < 8; ++m)
#pragma unroll
        for (int n = 0; n < 4; ++n)
            acc[m][n] = (f32x4)0.0f;

    // ---- prologue: tile0 (all 4 regions) + tile1 K0 ----
    stage_region<0, 0, 0>(lds0, Xb, m0, 0,  tid, wid);
    stage_region<0, 1, 0>(lds0, Wb, n0, 0,  tid, wid);
    stage_region<0, 0, 1>(lds0, Xb, m0, 32, tid, wid);
    stage_region<0, 1, 1>(lds0, Wb, n0, 32, tid, wid);
    stage_region<1, 0, 0>(lds0, Xb, m0, 64, tid, wid);
    stage_region<1, 1, 0>(lds0, Wb, n0, 64, tid, wid);
    asm volatile("s_waitcnt vmcnt(8)" ::: "memory");   // tile0.K0 landed
    asm volatile("s_barrier" ::: "memory");

    // ---- main loop: 2 K-tiles per iteration, 8 phases ----
#pragma unroll 1
    for (int it = 0, te = 0; it < NKT / 2; ++it, te += 2) {
        //    <RBUF,RKH,MG,  SBUF,SMAT,SKH, SOFF, VMW>
        phase<0, 0, 0,  1, 0, 1,  1, false>(lds0, acc, Xb, Wb, m0, n0, te, arow, brow, ps, tid, wid);
        phase<0, 0, 1,  1, 1, 1,  1, true >(lds0, acc, Xb, Wb, m0, n0, te, arow, brow, ps, tid, wid);
        phase<0, 1, 0,  0, 0, 0,  2, false>(lds0, acc, Xb, Wb, m0, n0, te, arow, brow, ps, tid, wid);
        phase<0, 1, 1,  0, 1, 0,  2, true >(lds0, acc, Xb, Wb, m0, n0, te, arow, brow, ps, tid, wid);
        phase<1, 0, 0,  0, 0, 1,  2, false>(lds0, acc, Xb, Wb, m0, n0, te, arow, brow, ps, tid, wid);
        phase<1, 0, 1,  0, 1, 1,  2, true >(lds0, acc, Xb, Wb, m0, n0, te, arow, brow, ps, tid, wid);
        phase<1, 1, 0,  1, 0, 0,  3, false>(lds0, acc, Xb, Wb, m0, n0, te, arow, brow, ps, tid, wid);
        phase<1, 1, 1,  1, 1, 0,  3, true >(lds0, acc, Xb, Wb, m0, n0, te, arow, brow, ps, tid, wid);
    }
    asm volatile("s_waitcnt vmcnt(0) lgkmcnt(0)" ::: "memory");
    asm volatile("s_barrier" ::: "memory");

    // ---- epilogue: exp-sum per token row + selected logit ----
#pragma unroll
    for (int m = 0; m < 8; ++m) {
#pragma unroll
        for (int j = 0; j < 4; ++j) {
            int row = m0 + wr * 128 + m * 16 + g * 4 + j;
            float s = 0.f;
#pragma unroll
            for (int n = 0; n < 4; ++n)
                s += __expf(acc[m][n][j]);
            s += __shfl_xor(s, 1, 64);
            s += __shfl_xor(s, 2, 64);
            s += __shfl_xor(s, 4, 64);
            s += __shfl_xor(s, 8, 64);
            if (l16 == 0) atomicAdd(&S[row], s);

            int id   = ids[row];
            int base = n0 + wc * 64 + l16;
#pragma unroll
            for (int n = 0; n < 4; ++n)
                if (id == base + n * 16) SEL[row] = acc[m][n][j];
        }
    }
}

// ---------------------------------------------------------------------------
// Zero S accumulators (8192 floats).
// ---------------------------------------------------------------------------
__global__ void grpo_init(float* __restrict__ p)
{
    p[blockIdx.x * 1024 + threadIdx.x] = 0.f;
}

// ---------------------------------------------------------------------------
// logp in-place over SEL: lp = SEL - log(S).
// ---------------------------------------------------------------------------
__global__ __launch_bounds__(1024)
void grpo_prep(const float* __restrict__ S_p, const float* __restrict__ S_r,
               float* __restrict__ lp_p, float* __restrict__ lp_r)
{
    int i = blockIdx.x * 1024 + threadIdx.x;
    lp_p[i] = lp_p[i] - logf(S_p[i]);
    lp_r[i] = lp_r[i] - logf(S_r[i]);
}

// ---------------------------------------------------------------------------
// Exact rank-819 threshold (k = int(4096*0.2) = 819), parallel over 64 CUs.
// ---------------------------------------------------------------------------
__global__ __launch_bounds__(64)
void grpo_thresh(const float* __restrict__ lp_r, float* __restrict__ thr)
{
    __shared__ float sh[NTOK];
    for (int i = threadIdx.x; i < NTOK; i += 64) sh[i] = lp_r[i];
    __syncthreads();
    const float v = sh[blockIdx.x * 64 + threadIdx.x];
    int lt = 0, eq = 0;
#pragma unroll 4
    for (int j = 0; j < NTOK; ++j) {
        float u = sh[j];
        lt += (u < v);
        eq += (u == v);
    }
    if (lt <= 818 && 818 < lt + eq) thr[0] = v;
}

// ---------------------------------------------------------------------------
// Final reductions -> 3 scalars. coef_1 == 1 exactly -> ppo = -adv, clip = 0.
// ---------------------------------------------------------------------------
__global__ __launch_bounds__(1024)
void grpo_final(const float* __restrict__ lp_p, const float* __restrict__ lp_r,
                const float* __restrict__ thr,
                const float* __restrict__ am, const float* __restrict__ adv,
                float* __restrict__ out)
{
    __shared__ double red[3][16];
    const int tid = threadIdx.x;
    const float t = thr[0];

    double s_loss = 0.0, s_kl = 0.0, s_am = 0.0;
    for (int i = tid; i < NTOK; i += 1024) {
        float a  = am[i];
        float pr = lp_r[i], pp = lp_p[i];
        float lr = pr - pp;
        float k3 = expf(lr) - lr - 1.0f;
        float kl = (pr <= t) ? k3 * 5.0f : 0.0f;
        float ad = adv[i / TT];
        float ptl = -ad + 0.04f * kl;
        s_loss += (double)(ptl * a);
        s_kl   += (double)(kl * a);
        s_am   += (double)a;
    }
#pragma unroll
    for (int off = 32; off; off >>= 1) {
        s_loss += __shfl_down(s_loss, off, 64);
        s_kl   += __shfl_down(s_kl,   off, 64);
        s_am   += __shfl_down(s_am,   off, 64);
    }
    const int wid = tid >> 6;
    if ((tid & 63) == 0) { red[0][wid] = s_loss; red[1][wid] = s_kl; red[2][wid] = s_am; }
    __syncthreads();
    if (tid == 0) {
        double L = 0, K = 0, A = 0;
        for (int w = 0; w < 16; ++w) { L += red[0][w]; K += red[1][w]; A += red[2][w]; }
        double norm = A < 1.0 ? 1.0 : A;
        out[0] = (float)(L / norm);
        out[1] = (float)(K / norm);
        out[2] = 0.0f;
    }
}

extern "C" void kernel_launch(void* const* d_in, const int* in_sizes, int n_in,
                              void* d_out, int out_size, void* d_ws, size_t ws_size,
                              hipStream_t stream)
{
    const float* X   = (const float*)d_in[0];
    const float* W   = (const float*)d_in[1];
    const int*   ids = (const int*)  d_in[2];
    const float* am  = (const float*)d_in[3];
    const float* adv = (const float*)d_in[4];
    const float* Xr  = (const float*)d_in[5];
    const float* Wr  = (const float*)d_in[6];
    float* out = (float*)d_out;

    float* S_p  = (float*)d_ws;
    float* S_r  = S_p + NTOK;
    float* lp_p = S_r + NTOK;      // SEL_p, overwritten in-place by prep
    float* lp_r = lp_p + NTOK;     // SEL_r
    float* thr  = S_p;             // reused after S consumed

    const size_t bf16_off = 65536;
    const size_t nX = (size_t)NTOK * HH, nW = (size_t)VV * HH;

    bf16_t* Xb  = (bf16_t*)((char*)d_ws + bf16_off);
    bf16_t* Wb  = Xb + nX;
    bf16_t* Xrb = Wb + nW;
    bf16_t* Wrb = Xrb + nX;

    hipLaunchKernelGGL(grpo_init, dim3(8), dim3(1024), 0, stream, S_p);

    hipLaunchKernelGGL(grpo_cvt_bf16, dim3(1024), dim3(256), 0, stream, X,  Xb,  (int)(nX / 4));
    hipLaunchKernelGGL(grpo_cvt_bf16, dim3(2048), dim3(256), 0, stream, W,  Wb,  (int)(nW / 4));
    hipLaunchKernelGGL(grpo_cvt_bf16, dim3(1024), dim3(256), 0, stream, Xr, Xrb, (int)(nX / 4));
    hipLaunchKernelGGL(grpo_cvt_bf16, dim3(2048), dim3(256), 0, stream, Wr, Wrb, (int)(nW / 4));

    dim3 grid(NTOK / BM, VV / BN);   // 16 x 125; m fastest -> W panel L2 reuse
    hipLaunchKernelGGL(grpo_gemm8, grid, dim3(512), 0, stream, Xb,  Wb,  ids, S_p, lp_p);
    hipLaunchKernelGGL(grpo_gemm8, grid, dim3(512), 0, stream, Xrb, Wrb, ids, S_r, lp_r);

    hipLaunchKernelGGL(grpo_prep,   dim3(4),  dim3(1024), 0, stream, S_p, S_r, lp_p, lp_r);
    hipLaunchKernelGGL(grpo_thresh, dim3(64), dim3(64),   0, stream, lp_r, thr);
    hipLaunchKernelGGL(grpo_final,  dim3(1),  dim3(1024), 0, stream, lp_p, lp_r, thr, am, adv, out);
}

// Round 4
// 883.739 us; speedup vs baseline: 1.0625x; 1.0625x over previous
//
#include <hip/hip_runtime.h>
#include <hip/hip_bf16.h>

typedef __bf16 bf16_t;
typedef __bf16 bf16x4 __attribute__((ext_vector_type(4)));
typedef __bf16 bf16x8 __attribute__((ext_vector_type(8)));
typedef float f32x4 __attribute__((ext_vector_type(4)));

#define NTOK 4096   // B*T
#define TT   512
#define HH   1024
#define VV   32000

#define BM 256
#define BN 256
#define BK 64       // two K-slices of 32
#define NKT 16      // K-tiles = HH/BK

#define GLOBAL_AS(p) ((const __attribute__((address_space(1))) void*)(const void*)(p))
#define LDS_AS(p)    ((__attribute__((address_space(3))) void*)(void*)(p))

// ---------------------------------------------------------------------------
// f32 -> bf16 bulk convert (memory-bound pre-pass).
// ---------------------------------------------------------------------------
__global__ __launch_bounds__(256)
void grpo_cvt_bf16(const float* __restrict__ src, bf16_t* __restrict__ dst, int n4)
{
    int i = blockIdx.x * 256 + threadIdx.x;
    const int stride = gridDim.x * 256;
    for (; i < n4; i += stride) {
        f32x4 v = *(const f32x4*)(src + (size_t)i * 4);
        bf16x4 b;
#pragma unroll
        for (int e = 0; e < 4; ++e) b[e] = (bf16_t)v[e];
        *(bf16x4*)(dst + (size_t)i * 4) = b;
    }
}

// ---------------------------------------------------------------------------
// 8-phase 256x256 GEMM + logsumexp partial + selected-logit gather.
// LDS ring: lds[buf][mat][kh] = 8 regions of [256 rows][32 K-cols] bf16 (16KB).
// Swizzle (T2, fixed r4): phys 16B slot = logical ^ ((row>>1)&3)  (involution).
//   read slot&7 = 4*(row&1) + (g ^ ((row>>1)&3)) -> all 8 values, 2 lanes each
//   per 16-lane batch -> 2-way (free, m136). Old (row&3) collapsed to 4-way.
// gload_lds writes linearly; source address pre-swizzled; reads swizzled.
// ---------------------------------------------------------------------------
__device__ __forceinline__ bf16_t* region_ptr(bf16_t* lds0, int b, int mat, int kh)
{
    return lds0 + ((b * 2 + mat) * 2 + kh) * 8192;   // 256*32 bf16 per region
}

template<int SBUF, int SMAT, int SKH>
__device__ __forceinline__ void stage_region(bf16_t* lds0, const bf16_t* __restrict__ src,
                                             int row0, int kc, int tid, int wid)
{
    bf16_t* reg = region_ptr(lds0, SBUF, SMAT, SKH);
#pragma unroll
    for (int i = 0; i < 2; ++i) {
        const int f     = i * 512 + tid;                  // physical 16B chunk 0..1023
        const int row   = f >> 2;                         // 0..255
        const int lslot = (f & 3) ^ ((f >> 3) & 3);       // inverse swizzle ((row>>1)&3)
        const bf16_t* g = src + (size_t)(row0 + row) * HH + kc + lslot * 8;
        bf16_t* l = reg + (i * 512 + wid * 64) * 8;       // wave-uniform; HW adds lane*16B
        __builtin_amdgcn_global_load_lds(GLOBAL_AS(g), LDS_AS(l), 16, 0, 0);
    }
}

template<int RBUF, int RKH, int MG, int SBUF, int SMAT, int SKH, int SOFF, bool VMW>
__device__ __forceinline__ void phase(bf16_t* lds0, f32x4 (&acc)[8][4],
                                      const bf16_t* __restrict__ Xb,
                                      const bf16_t* __restrict__ Wb,
                                      int m0, int n0, int te,
                                      int arow, int brow, int ps, int tid, int wid)
{
    const bf16_t* Ar = region_ptr(lds0, RBUF, 0, RKH);
    const bf16_t* Br = region_ptr(lds0, RBUF, 1, RKH);

    bf16x8 af[4], bfr[4];
#pragma unroll
    for (int m = 0; m < 4; ++m)
        af[m] = *(const bf16x8*)(Ar + (arow + MG * 64 + m * 16) * 32 + ps * 8);
#pragma unroll
    for (int n = 0; n < 4; ++n)
        bfr[n] = *(const bf16x8*)(Br + (brow + n * 16) * 32 + ps * 8);

    // prefetch one region for a future K-tile (lands >=5 phases before its read)
    stage_region<SBUF, SMAT, SKH>(lds0, SMAT ? Wb : Xb, SMAT ? n0 : m0,
                                  ((te + SOFF) & (NKT - 1)) * BK + SKH * 32, tid, wid);

    asm volatile("s_barrier" ::: "memory");
    asm volatile("s_waitcnt lgkmcnt(0)" ::: "memory");
    __builtin_amdgcn_sched_barrier(0);

    __builtin_amdgcn_s_setprio(1);
#pragma unroll
    for (int m = 0; m < 4; ++m)
#pragma unroll
        for (int n = 0; n < 4; ++n)
            acc[MG * 4 + m][n] = __builtin_amdgcn_mfma_f32_16x16x32_bf16(
                af[m], bfr[n], acc[MG * 4 + m][n], 0, 0, 0);
    __builtin_amdgcn_s_setprio(0);

    if (VMW) asm volatile("s_waitcnt vmcnt(8)" ::: "memory");  // counted, never 0
    asm volatile("s_barrier" ::: "memory");
}

__global__ __launch_bounds__(512)
void grpo_gemm8(const bf16_t* __restrict__ Xb, const bf16_t* __restrict__ Wb,
                const int* __restrict__ ids,
                float* __restrict__ S, float* __restrict__ SEL)
{
    __shared__ bf16_t lds[2][2][2][256][32];   // 128 KiB
    bf16_t* lds0 = &lds[0][0][0][0][0];

    const int tid  = threadIdx.x;
    const int lane = tid & 63;
    const int wid  = tid >> 6;
    const int wr   = wid >> 2;        // 0..1  (M split)
    const int wc   = wid & 3;         // 0..3  (N split)
    const int l16  = lane & 15;
    const int g    = lane >> 4;                 // logical K-slot
    const int ps   = g ^ ((l16 >> 1) & 3);      // physical (swizzled) K-slot
    const int arow = wr * 128 + l16;
    const int brow = wc * 64 + l16;

    const int m0 = blockIdx.x * BM;
    const int n0 = blockIdx.y * BN;

    f32x4 acc[8][4];
#pragma unroll
    for (int m = 0; m < 8; ++m)
#pragma unroll
        for (int n = 0; n < 4; ++n)
            acc[m][n] = (f32x4)0.0f;

    // ---- prologue: tile0 (all 4 regions) + tile1 K0 ----
    stage_region<0, 0, 0>(lds0, Xb, m0, 0,  tid, wid);
    stage_region<0, 1, 0>(lds0, Wb, n0, 0,  tid, wid);
    stage_region<0, 0, 1>(lds0, Xb, m0, 32, tid, wid);
    stage_region<0, 1, 1>(lds0, Wb, n0, 32, tid, wid);
    stage_region<1, 0, 0>(lds0, Xb, m0, 64, tid, wid);
    stage_region<1, 1, 0>(lds0, Wb, n0, 64, tid, wid);
    asm volatile("s_waitcnt vmcnt(8)" ::: "memory");   // tile0.K0 landed
    asm volatile("s_barrier" ::: "memory");

    // ---- main loop: 2 K-tiles per iteration, 8 phases ----
#pragma unroll 1
    for (int it = 0, te = 0; it < NKT / 2; ++it, te += 2) {
        //    <RBUF,RKH,MG,  SBUF,SMAT,SKH, SOFF, VMW>
        phase<0, 0, 0,  1, 0, 1,  1, false>(lds0, acc, Xb, Wb, m0, n0, te, arow, brow, ps, tid, wid);
        phase<0, 0, 1,  1, 1, 1,  1, true >(lds0, acc, Xb, Wb, m0, n0, te, arow, brow, ps, tid, wid);
        phase<0, 1, 0,  0, 0, 0,  2, false>(lds0, acc, Xb, Wb, m0, n0, te, arow, brow, ps, tid, wid);
        phase<0, 1, 1,  0, 1, 0,  2, true >(lds0, acc, Xb, Wb, m0, n0, te, arow, brow, ps, tid, wid);
        phase<1, 0, 0,  0, 0, 1,  2, false>(lds0, acc, Xb, Wb, m0, n0, te, arow, brow, ps, tid, wid);
        phase<1, 0, 1,  0, 1, 1,  2, true >(lds0, acc, Xb, Wb, m0, n0, te, arow, brow, ps, tid, wid);
        phase<1, 1, 0,  1, 0, 0,  3, false>(lds0, acc, Xb, Wb, m0, n0, te, arow, brow, ps, tid, wid);
        phase<1, 1, 1,  1, 1, 0,  3, true >(lds0, acc, Xb, Wb, m0, n0, te, arow, brow, ps, tid, wid);
    }
    asm volatile("s_waitcnt vmcnt(0) lgkmcnt(0)" ::: "memory");
    asm volatile("s_barrier" ::: "memory");

    // ---- epilogue: exp-sum per token row + selected logit ----
#pragma unroll
    for (int m = 0; m < 8; ++m) {
#pragma unroll
        for (int j = 0; j < 4; ++j) {
            int row = m0 + wr * 128 + m * 16 + g * 4 + j;
            float s = 0.f;
#pragma unroll
            for (int n = 0; n < 4; ++n)
                s += __expf(acc[m][n][j]);
            s += __shfl_xor(s, 1, 64);
            s += __shfl_xor(s, 2, 64);
            s += __shfl_xor(s, 4, 64);
            s += __shfl_xor(s, 8, 64);
            if (l16 == 0) atomicAdd(&S[row], s);

            int id   = ids[row];
            int base = n0 + wc * 64 + l16;
#pragma unroll
            for (int n = 0; n < 4; ++n)
                if (id == base + n * 16) SEL[row] = acc[m][n][j];
        }
    }
}

// ---------------------------------------------------------------------------
// Zero S accumulators (8192 floats).
// ---------------------------------------------------------------------------
__global__ void grpo_init(float* __restrict__ p)
{
    p[blockIdx.x * 1024 + threadIdx.x] = 0.f;
}

// ---------------------------------------------------------------------------
// logp in-place over SEL: lp = SEL - log(S).
// ---------------------------------------------------------------------------
__global__ __launch_bounds__(1024)
void grpo_prep(const float* __restrict__ S_p, const float* __restrict__ S_r,
               float* __restrict__ lp_p, float* __restrict__ lp_r)
{
    int i = blockIdx.x * 1024 + threadIdx.x;
    lp_p[i] = lp_p[i] - logf(S_p[i]);
    lp_r[i] = lp_r[i] - logf(S_r[i]);
}

// ---------------------------------------------------------------------------
// Exact rank-819 threshold (k = int(4096*0.2) = 819), parallel over 64 CUs.
// ---------------------------------------------------------------------------
__global__ __launch_bounds__(64)
void grpo_thresh(const float* __restrict__ lp_r, float* __restrict__ thr)
{
    __shared__ float sh[NTOK];
    for (int i = threadIdx.x; i < NTOK; i += 64) sh[i] = lp_r[i];
    __syncthreads();
    const float v = sh[blockIdx.x * 64 + threadIdx.x];
    int lt = 0, eq = 0;
#pragma unroll 4
    for (int j = 0; j < NTOK; ++j) {
        float u = sh[j];
        lt += (u < v);
        eq += (u == v);
    }
    if (lt <= 818 && 818 < lt + eq) thr[0] = v;
}

// ---------------------------------------------------------------------------
// Final reductions -> 3 scalars. coef_1 == 1 exactly -> ppo = -adv, clip = 0.
// ---------------------------------------------------------------------------
__global__ __launch_bounds__(1024)
void grpo_final(const float* __restrict__ lp_p, const float* __restrict__ lp_r,
                const float* __restrict__ thr,
                const float* __restrict__ am, const float* __restrict__ adv,
                float* __restrict__ out)
{
    __shared__ double red[3][16];
    const int tid = threadIdx.x;
    const float t = thr[0];

    double s_loss = 0.0, s_kl = 0.0, s_am = 0.0;
    for (int i = tid; i < NTOK; i += 1024) {
        float a  = am[i];
        float pr = lp_r[i], pp = lp_p[i];
        float lr = pr - pp;
        float k3 = expf(lr) - lr - 1.0f;
        float kl = (pr <= t) ? k3 * 5.0f : 0.0f;
        float ad = adv[i / TT];
        float ptl = -ad + 0.04f * kl;
        s_loss += (double)(ptl * a);
        s_kl   += (double)(kl * a);
        s_am   += (double)a;
    }
#pragma unroll
    for (int off = 32; off; off >>= 1) {
        s_loss += __shfl_down(s_loss, off, 64);
        s_kl   += __shfl_down(s_kl,   off, 64);
        s_am   += __shfl_down(s_am,   off, 64);
    }
    const int wid = tid >> 6;
    if ((tid & 63) == 0) { red[0][wid] = s_loss; red[1][wid] = s_kl; red[2][wid] = s_am; }
    __syncthreads();
    if (tid == 0) {
        double L = 0, K = 0, A = 0;
        for (int w = 0; w < 16; ++w) { L += red[0][w]; K += red[1][w]; A += red[2][w]; }
        double norm = A < 1.0 ? 1.0 : A;
        out[0] = (float)(L / norm);
        out[1] = (float)(K / norm);
        out[2] = 0.0f;
    }
}

extern "C" void kernel_launch(void* const* d_in, const int* in_sizes, int n_in,
                              void* d_out, int out_size, void* d_ws, size_t ws_size,
                              hipStream_t stream)
{
    const float* X   = (const float*)d_in[0];
    const float* W   = (const float*)d_in[1];
    const int*   ids = (const int*)  d_in[2];
    const float* am  = (const float*)d_in[3];
    const float* adv = (const float*)d_in[4];
    const float* Xr  = (const float*)d_in[5];
    const float* Wr  = (const float*)d_in[6];
    float* out = (float*)d_out;

    float* S_p  = (float*)d_ws;
    float* S_r  = S_p + NTOK;
    float* lp_p = S_r + NTOK;      // SEL_p, overwritten in-place by prep
    float* lp_r = lp_p + NTOK;     // SEL_r
    float* thr  = S_p;             // reused after S consumed

    const size_t bf16_off = 65536;
    const size_t nX = (size_t)NTOK * HH, nW = (size_t)VV * HH;

    bf16_t* Xb  = (bf16_t*)((char*)d_ws + bf16_off);
    bf16_t* Wb  = Xb + nX;
    bf16_t* Xrb = Wb + nW;
    bf16_t* Wrb = Xrb + nX;

    hipLaunchKernelGGL(grpo_init, dim3(8), dim3(1024), 0, stream, S_p);

    hipLaunchKernelGGL(grpo_cvt_bf16, dim3(1024), dim3(256), 0, stream, X,  Xb,  (int)(nX / 4));
    hipLaunchKernelGGL(grpo_cvt_bf16, dim3(2048), dim3(256), 0, stream, W,  Wb,  (int)(nW / 4));
    hipLaunchKernelGGL(grpo_cvt_bf16, dim3(1024), dim3(256), 0, stream, Xr, Xrb, (int)(nX / 4));
    hipLaunchKernelGGL(grpo_cvt_bf16, dim3(2048), dim3(256), 0, stream, Wr, Wrb, (int)(nW / 4));

    dim3 grid(NTOK / BM, VV / BN);   // 16 x 125; m fastest -> W panel L2 reuse
    hipLaunchKernelGGL(grpo_gemm8, grid, dim3(512), 0, stream, Xb,  Wb,  ids, S_p, lp_p);
    hipLaunchKernelGGL(grpo_gemm8, grid, dim3(512), 0, stream, Xrb, Wrb, ids, S_r, lp_r);

    hipLaunchKernelGGL(grpo_prep,   dim3(4),  dim3(1024), 0, stream, S_p, S_r, lp_p, lp_r);
    hipLaunchKernelGGL(grpo_thresh, dim3(64), dim3(64),   0, stream, lp_r, thr);
    hipLaunchKernelGGL(grpo_final,  dim3(1),  dim3(1024), 0, stream, lp_p, lp_r, thr, am, adv, out);
}